// Round 2
// baseline (2139.724 us; speedup 1.0000x reference)
//
#include <hip/hip_runtime.h>

#define N_IN   262144
#define N_OUT  262144
#define KOFF   27
#define MPAIR  131072                 // 2^17
#define NTOT   (KOFF * MPAIR)         // 3538944
#define C      64
#define RPB    128                    // output rows per gather block
#define NBLK   (N_OUT / RPB)          // 2048
#define NKEY   (NBLK * KOFF)          // 55296
#define SCANB  (NKEY / 256)           // 216
#define EPS    1e-5f
#define NEG_SLOPE 0.01f

typedef unsigned int u32;

// ---------------------------------------------------------------------------
// Counting sort of the 3.54M entries by key = (om/128)*27 + k.
// Entry payload packs (local_row 7b | k 5b | im 18b) into one u32.
// ---------------------------------------------------------------------------
__global__ __launch_bounds__(256) void hist_kernel(
    const int* __restrict__ out_map, u32* __restrict__ counts)
{
    int i = blockIdx.x * 256 + threadIdx.x;     // i = k*MPAIR + m
    int k = i >> 17;
    int om = out_map[i];
    atomicAdd(&counts[(u32)(om >> 7) * KOFF + (u32)k], 1u);
}

__global__ __launch_bounds__(256) void scan1_kernel(
    const u32* __restrict__ counts, u32* __restrict__ partial, u32* __restrict__ bsums)
{
    __shared__ u32 sh[256];
    int t = threadIdx.x, g = blockIdx.x * 256 + t;
    u32 v = counts[g];
    sh[t] = v; __syncthreads();
    for (int off = 1; off < 256; off <<= 1) {
        u32 a = (t >= off) ? sh[t - off] : 0u;
        __syncthreads(); sh[t] += a; __syncthreads();
    }
    partial[g] = sh[t] - v;                      // exclusive within block
    if (t == 255) bsums[blockIdx.x] = sh[t];     // block total
}

__global__ __launch_bounds__(256) void scan2_kernel(u32* __restrict__ bsums)
{
    __shared__ u32 sh[256];
    int t = threadIdx.x;
    u32 v = (t < SCANB) ? bsums[t] : 0u;
    sh[t] = v; __syncthreads();
    for (int off = 1; off < 256; off <<= 1) {
        u32 a = (t >= off) ? sh[t - off] : 0u;
        __syncthreads(); sh[t] += a; __syncthreads();
    }
    if (t < SCANB) bsums[t] = sh[t] - v;         // exclusive block bases
}

__global__ __launch_bounds__(256) void scan3_kernel(
    const u32* __restrict__ partial, const u32* __restrict__ bsums,
    u32* __restrict__ offsets, u32* __restrict__ cursor)
{
    int g = blockIdx.x * 256 + threadIdx.x;
    u32 o = partial[g] + bsums[blockIdx.x];
    offsets[g] = o; cursor[g] = o;
    if (g == 0) offsets[NKEY] = NTOT;            // sentinel
}

__global__ __launch_bounds__(256) void scatter_kernel(
    const int* __restrict__ in_map, const int* __restrict__ out_map,
    u32* __restrict__ cursor, u32* __restrict__ sorted)
{
    int i = blockIdx.x * 256 + threadIdx.x;
    int k = i >> 17;
    int om = out_map[i];
    u32 im = (u32)in_map[i];
    u32 key = (u32)(om >> 7) * KOFF + (u32)k;
    u32 pos = atomicAdd(&cursor[key], 1u);
    sorted[pos] = ((u32)(om & 127) << 23) | ((u32)k << 18) | im;
}

// ---------------------------------------------------------------------------
// Gather: block owns 128 out rows in a 32 KB LDS accumulator. lane = cout.
// Per k-group: W[k] column in 64 VGPRs (launch_bounds(256,4) -> 128 VGPR cap),
// entries streamed with feats-row prefetch overlapping the 64-FMA dot.
// ds_add_f32 accumulation, one coalesced 256 B store per row, fused stats.
// ---------------------------------------------------------------------------
__global__ __launch_bounds__(256, 4) void gather_kernel(
    const float* __restrict__ feats, const float* __restrict__ W,
    const u32* __restrict__ offsets, const u32* __restrict__ sorted,
    float* __restrict__ out, float* __restrict__ stats)
{
    __shared__ float accs[RPB][C];        // 32 KB row accumulators
    __shared__ float frow[4][C];          // per-wave staging (1 KB)
    const int t = threadIdx.x, lane = t & 63, wave = t >> 6;
    const int b = blockIdx.x;

    {   // zero accumulators
        float4* az = (float4*)&accs[0][0];
        #pragma unroll
        for (int j = 0; j < RPB * C / 4 / 256; ++j)
            az[j * 256 + t] = make_float4(0.f, 0.f, 0.f, 0.f);
    }
    __syncthreads();

    for (int kk = wave; kk < KOFF; kk += 4) {   // each k-group owned by one wave
        const u32 start = offsets[b * KOFF + kk];
        const u32 end   = offsets[b * KOFF + kk + 1];
        if (start == end) continue;

        float wcol[C];                            // W[kk][:, lane]
        const float* Wk = W + kk * C * C;
        #pragma unroll
        for (int i = 0; i < C; ++i) wcol[i] = Wk[i * C + lane];

        u32 ent = sorted[start];
        float fcur = feats[(size_t)(ent & 0x3FFFFu) * C + lane];

        for (u32 e = start; e < end; ++e) {
            const int lrow = (int)(ent >> 23);
            frow[wave][lane] = fcur;
            if (e + 1 < end) {                    // prefetch next row (hidden by FMAs)
                ent  = sorted[e + 1];
                fcur = feats[(size_t)(ent & 0x3FFFFu) * C + lane];
            }
            float a = 0.f;
            const float4* f4 = (const float4*)&frow[wave][0];
            #pragma unroll
            for (int j = 0; j < 16; ++j) {        // uniform-addr LDS broadcast
                float4 f = f4[j];
                a = fmaf(f.x, wcol[4 * j + 0], a);
                a = fmaf(f.y, wcol[4 * j + 1], a);
                a = fmaf(f.z, wcol[4 * j + 2], a);
                a = fmaf(f.w, wcol[4 * j + 3], a);
            }
            atomicAdd(&accs[lrow][lane], a);      // ds_add_f32
        }
    }
    __syncthreads();

    // store rows + fused per-channel stats
    const int col4 = t & 15, rowg = t >> 4;
    float4 s4 = make_float4(0.f, 0.f, 0.f, 0.f);
    float4 q4 = make_float4(0.f, 0.f, 0.f, 0.f);
    float4* outv = (float4*)out;
    #pragma unroll
    for (int r = rowg; r < RPB; r += 16) {
        float4 v = *((const float4*)&accs[r][0] + col4);
        outv[(size_t)(b * RPB + r) * 16 + col4] = v;
        s4.x += v.x; s4.y += v.y; s4.z += v.z; s4.w += v.w;
        q4.x = fmaf(v.x, v.x, q4.x); q4.y = fmaf(v.y, v.y, q4.y);
        q4.z = fmaf(v.z, v.z, q4.z); q4.w = fmaf(v.w, v.w, q4.w);
    }
    __syncthreads();
    float4* sc = (float4*)&accs[0][0];            // reuse acc LDS as scratch
    sc[t] = s4; sc[256 + t] = q4;
    __syncthreads();
    if (t < 16) {
        float4 ts = make_float4(0.f, 0.f, 0.f, 0.f);
        float4 tq = make_float4(0.f, 0.f, 0.f, 0.f);
        for (int j = 0; j < 16; ++j) {
            float4 a = sc[j * 16 + t], bq = sc[256 + j * 16 + t];
            ts.x += a.x; ts.y += a.y; ts.z += a.z; ts.w += a.w;
            tq.x += bq.x; tq.y += bq.y; tq.z += bq.z; tq.w += bq.w;
        }
        const int c0 = t * 4;
        unsafeAtomicAdd(&stats[c0 + 0], ts.x);
        unsafeAtomicAdd(&stats[c0 + 1], ts.y);
        unsafeAtomicAdd(&stats[c0 + 2], ts.z);
        unsafeAtomicAdd(&stats[c0 + 3], ts.w);
        unsafeAtomicAdd(&stats[C + c0 + 0], tq.x);
        unsafeAtomicAdd(&stats[C + c0 + 1], tq.y);
        unsafeAtomicAdd(&stats[C + c0 + 2], tq.z);
        unsafeAtomicAdd(&stats[C + c0 + 3], tq.w);
    }
}

// ---------------------------------------------------------------------------
// In-place BN (affine) + LeakyReLU, float4-vectorized.
// ---------------------------------------------------------------------------
__global__ __launch_bounds__(256) void bn_kernel(
    float* __restrict__ out, const float* __restrict__ stats,
    const float* __restrict__ gamma, const float* __restrict__ beta)
{
    __shared__ __align__(16) float s_scale[C];
    __shared__ __align__(16) float s_shift[C];
    if (threadIdx.x < C) {
        const float inv_n = 1.0f / (float)N_OUT;
        float mean = stats[threadIdx.x] * inv_n;
        float var  = stats[C + threadIdx.x] * inv_n - mean * mean;
        float sc   = gamma[threadIdx.x] * rsqrtf(var + EPS);
        s_scale[threadIdx.x] = sc;
        s_shift[threadIdx.x] = beta[threadIdx.x] - mean * sc;
    }
    __syncthreads();

    const int col4 = threadIdx.x & 15;
    const int rowg = threadIdx.x >> 4;
    const float4 sc4 = *(const float4*)&s_scale[col4 * 4];
    const float4 sh4 = *(const float4*)&s_shift[col4 * 4];

    for (int row = blockIdx.x * 16 + rowg; row < N_OUT; row += gridDim.x * 16) {
        float4* p = (float4*)(out + (size_t)row * C + col4 * 4);
        float4 v = *p;
        v.x = fmaf(v.x, sc4.x, sh4.x);
        v.y = fmaf(v.y, sc4.y, sh4.y);
        v.z = fmaf(v.z, sc4.z, sh4.z);
        v.w = fmaf(v.w, sc4.w, sh4.w);
        v.x = v.x >= 0.f ? v.x : NEG_SLOPE * v.x;
        v.y = v.y >= 0.f ? v.y : NEG_SLOPE * v.y;
        v.z = v.z >= 0.f ? v.z : NEG_SLOPE * v.z;
        v.w = v.w >= 0.f ? v.w : NEG_SLOPE * v.w;
        *p = v;
    }
}

extern "C" void kernel_launch(void* const* d_in, const int* in_sizes, int n_in,
                              void* d_out, int out_size, void* d_ws, size_t ws_size,
                              hipStream_t stream) {
    const float* feats  = (const float*)d_in[0];
    const float* W      = (const float*)d_in[1];
    const float* gamma  = (const float*)d_in[2];
    const float* beta   = (const float*)d_in[3];
    const int*  in_map  = (const int*)d_in[4];
    const int*  out_map = (const int*)d_in[5];

    float* out = (float*)d_out;

    // workspace layout (u32-aligned; ~15.2 MB total)
    u32* counts  = (u32*)d_ws;            // NKEY
    u32* partial = counts  + NKEY;        // NKEY
    u32* bsums   = partial + NKEY;        // 256
    u32* offsets = bsums   + 256;         // NKEY + 1
    u32* cursor  = offsets + NKEY + 16;   // NKEY
    u32* sorted  = cursor  + NKEY;        // NTOT
    float* stats = (float*)(sorted + NTOT);  // 128

    hipMemsetAsync(counts, 0, NKEY * sizeof(u32), stream);
    hipMemsetAsync(stats, 0, 2 * C * sizeof(float), stream);

    hist_kernel   <<<NTOT / 256, 256, 0, stream>>>(out_map, counts);
    scan1_kernel  <<<SCANB,      256, 0, stream>>>(counts, partial, bsums);
    scan2_kernel  <<<1,          256, 0, stream>>>(bsums);
    scan3_kernel  <<<SCANB,      256, 0, stream>>>(partial, bsums, offsets, cursor);
    scatter_kernel<<<NTOT / 256, 256, 0, stream>>>(in_map, out_map, cursor, sorted);
    gather_kernel <<<NBLK,       256, 0, stream>>>(feats, W, offsets, sorted, out, stats);
    bn_kernel     <<<512,        256, 0, stream>>>(out, stats, gamma, beta);
}

// Round 3
// 1652.169 us; speedup vs baseline: 1.2951x; 1.2951x over previous
//
#include <hip/hip_runtime.h>

#define N_IN   262144
#define N_OUT  262144
#define KOFF   27
#define MPAIR  131072                 // 2^17
#define NTOT   (KOFF * MPAIR)         // 3538944
#define C      64
#define RPB    128                    // output rows per gather block
#define NBLK   (N_OUT / RPB)          // 2048
#define NKEY   (NBLK * KOFF)          // 55296
#define SCANB  (NKEY / 256)           // 216
#define ASTRIDE 68                    // LDS acc row stride (floats): 16B-aligned, +4 banks/row
#define EPS    1e-5f
#define NEG_SLOPE 0.01f

typedef unsigned int u32;
typedef _Float16 half8 __attribute__((ext_vector_type(8)));
typedef float floatx4 __attribute__((ext_vector_type(4)));

// ---------------------------------------------------------------------------
// Counting sort by key = (om>>7)*27 + k. Payload: (lrow 7b | k 5b | im 18b).
// ---------------------------------------------------------------------------
__global__ __launch_bounds__(256) void hist_kernel(
    const int* __restrict__ out_map, u32* __restrict__ counts)
{
    int i = blockIdx.x * 256 + threadIdx.x;     // i = k*MPAIR + m
    int k = i >> 17;
    int om = out_map[i];
    atomicAdd(&counts[(u32)(om >> 7) * KOFF + (u32)k], 1u);
}

__global__ __launch_bounds__(256) void scan1_kernel(
    const u32* __restrict__ counts, u32* __restrict__ partial, u32* __restrict__ bsums)
{
    __shared__ u32 sh[256];
    int t = threadIdx.x, g = blockIdx.x * 256 + t;
    u32 v = counts[g];
    sh[t] = v; __syncthreads();
    for (int off = 1; off < 256; off <<= 1) {
        u32 a = (t >= off) ? sh[t - off] : 0u;
        __syncthreads(); sh[t] += a; __syncthreads();
    }
    partial[g] = sh[t] - v;
    if (t == 255) bsums[blockIdx.x] = sh[t];
}

__global__ __launch_bounds__(256) void scan2_kernel(u32* __restrict__ bsums)
{
    __shared__ u32 sh[256];
    int t = threadIdx.x;
    u32 v = (t < SCANB) ? bsums[t] : 0u;
    sh[t] = v; __syncthreads();
    for (int off = 1; off < 256; off <<= 1) {
        u32 a = (t >= off) ? sh[t - off] : 0u;
        __syncthreads(); sh[t] += a; __syncthreads();
    }
    if (t < SCANB) bsums[t] = sh[t] - v;
}

__global__ __launch_bounds__(256) void scan3_kernel(
    const u32* __restrict__ partial, const u32* __restrict__ bsums,
    u32* __restrict__ offsets, u32* __restrict__ cursor)
{
    int g = blockIdx.x * 256 + threadIdx.x;
    u32 o = partial[g] + bsums[blockIdx.x];
    offsets[g] = o; cursor[g] = o;
    if (g == 0) offsets[NKEY] = NTOT;
}

__global__ __launch_bounds__(256) void scatter_kernel(
    const int* __restrict__ in_map, const int* __restrict__ out_map,
    u32* __restrict__ cursor, u32* __restrict__ sorted)
{
    int i = blockIdx.x * 256 + threadIdx.x;
    int k = i >> 17;
    int om = out_map[i];
    u32 im = (u32)in_map[i];
    u32 key = (u32)(om >> 7) * KOFF + (u32)k;
    u32 pos = atomicAdd(&cursor[key], 1u);
    sorted[pos] = ((u32)(om & 127) << 23) | ((u32)k << 18) | im;
}

// ---------------------------------------------------------------------------
// Pre-swizzle W into MFMA B-operand layout, fp16.
// Bh[((k*4 + ntile)*2 + kchunk)*64 + lane][j] = W[k][kchunk*32 + (lane>>4)*8 + j][ntile*16 + (lane&15)]
// ---------------------------------------------------------------------------
__global__ __launch_bounds__(256) void prep_kernel(
    const float* __restrict__ W, _Float16* __restrict__ Bh)
{
    int id = blockIdx.x * 256 + threadIdx.x;
    if (id >= KOFF * 4 * 2 * 64) return;
    int lane = id & 63;
    int c    = (id >> 6) & 1;
    int t    = (id >> 7) & 3;
    int k    = id >> 9;
    int n  = t * 16 + (lane & 15);
    int kb = c * 32 + (lane >> 4) * 8;
    _Float16* dst = Bh + (size_t)id * 8;
    #pragma unroll
    for (int j = 0; j < 8; ++j)
        dst[j] = (_Float16)W[((size_t)k * 64 + kb + j) * 64 + n];
}

__device__ inline half8 cvt8(float4 u, float4 v) {
    half8 r;
    r[0] = (_Float16)u.x; r[1] = (_Float16)u.y; r[2] = (_Float16)u.z; r[3] = (_Float16)u.w;
    r[4] = (_Float16)v.x; r[5] = (_Float16)v.y; r[6] = (_Float16)v.z; r[7] = (_Float16)v.w;
    return r;
}

// ---------------------------------------------------------------------------
// Gather-MFMA: block owns 128 out rows in padded LDS accumulator. Each wave
// owns k-groups kk = wave, wave+4, ... Entries processed in 16-row MFMA tiles
// (4 N-tiles x 2 K-chunks fp16 -> fp32). A-frags gathered straight from
// global (32 B/lane/chunk); B-frags register-resident per k-group; 2-deep
// pipeline on the ent->feats chain. C scattered via ds_add_f32.
// ---------------------------------------------------------------------------
__global__ __launch_bounds__(256, 4) void gather_kernel(
    const float* __restrict__ feats, const half8* __restrict__ Bh,
    const u32* __restrict__ offsets, const u32* __restrict__ sorted,
    float* __restrict__ out, float* __restrict__ stats)
{
    __shared__ float accs[RPB * ASTRIDE];     // 34816 B
    const int t    = threadIdx.x;
    const int lane = t & 63, wave = t >> 6;
    const int quad = lane >> 4, m16 = lane & 15;
    const int b = blockIdx.x;

    {   // zero accumulators (2176 float4)
        float4* az = (float4*)accs;
        for (int i = t; i < RPB * ASTRIDE / 4; i += 256)
            az[i] = make_float4(0.f, 0.f, 0.f, 0.f);
    }
    __syncthreads();

    for (int kk = wave; kk < KOFF; kk += 4) {
        const u32 start = offsets[b * KOFF + kk];
        const u32 end   = offsets[b * KOFF + kk + 1];
        if (start == end) continue;

        const int kb = kk * 8;                 // 8 B-frags for this k
        half8 b00 = Bh[(kb + 0) * 64 + lane];  // ntile0, kchunk0
        half8 b01 = Bh[(kb + 1) * 64 + lane];  // ntile0, kchunk1
        half8 b10 = Bh[(kb + 2) * 64 + lane];
        half8 b11 = Bh[(kb + 3) * 64 + lane];
        half8 b20 = Bh[(kb + 4) * 64 + lane];
        half8 b21 = Bh[(kb + 5) * 64 + lane];
        half8 b30 = Bh[(kb + 6) * 64 + lane];
        half8 b31 = Bh[(kb + 7) * 64 + lane];

        // pipeline prologue: tile 0's entry + feats
        u32 eidx = start + m16;
        u32 ent  = sorted[eidx < end ? eidx : end - 1];
        const float4* rp = (const float4*)(feats + (size_t)(ent & 0x3FFFFu) * C + quad * 8);
        float4 f0 = rp[0], f1 = rp[1], f2 = rp[8], f3 = rp[9];

        for (u32 base = start; base < end; base += 16) {
            const u32 ent_c = ent;
            float4 g0 = f0, g1 = f1, g2 = f2, g3 = f3;

            if (base + 16 < end) {             // prefetch next tile
                eidx = base + 16 + m16;
                ent  = sorted[eidx < end ? eidx : end - 1];
                rp = (const float4*)(feats + (size_t)(ent & 0x3FFFFu) * C + quad * 8);
                f0 = rp[0]; f1 = rp[1]; f2 = rp[8]; f3 = rp[9];
            }

            half8 a0 = cvt8(g0, g1);           // cin quad*8..+7
            half8 a1 = cvt8(g2, g3);           // cin 32+quad*8..+7

            floatx4 c0 = {0.f, 0.f, 0.f, 0.f};
            floatx4 c1 = {0.f, 0.f, 0.f, 0.f};
            floatx4 c2 = {0.f, 0.f, 0.f, 0.f};
            floatx4 c3 = {0.f, 0.f, 0.f, 0.f};
            c0 = __builtin_amdgcn_mfma_f32_16x16x32_f16(a0, b00, c0, 0, 0, 0);
            c0 = __builtin_amdgcn_mfma_f32_16x16x32_f16(a1, b01, c0, 0, 0, 0);
            c1 = __builtin_amdgcn_mfma_f32_16x16x32_f16(a0, b10, c1, 0, 0, 0);
            c1 = __builtin_amdgcn_mfma_f32_16x16x32_f16(a1, b11, c1, 0, 0, 0);
            c2 = __builtin_amdgcn_mfma_f32_16x16x32_f16(a0, b20, c2, 0, 0, 0);
            c2 = __builtin_amdgcn_mfma_f32_16x16x32_f16(a1, b21, c2, 0, 0, 0);
            c3 = __builtin_amdgcn_mfma_f32_16x16x32_f16(a0, b30, c3, 0, 0, 0);
            c3 = __builtin_amdgcn_mfma_f32_16x16x32_f16(a1, b31, c3, 0, 0, 0);

            // C layout: row m = quad*4 + i (reg i), col = ntile*16 + m16
            #pragma unroll
            for (int i = 0; i < 4; ++i) {
                const int m = quad * 4 + i;
                const u32 em = __shfl(ent_c, m);
                if (base + (u32)m < end) {
                    float* ap = &accs[(em >> 23) * ASTRIDE];
                    atomicAdd(&ap[ 0 + m16], c0[i]);
                    atomicAdd(&ap[16 + m16], c1[i]);
                    atomicAdd(&ap[32 + m16], c2[i]);
                    atomicAdd(&ap[48 + m16], c3[i]);
                }
            }
        }
    }
    __syncthreads();

    // epilogue: coalesced row stores + fused per-channel stats
    const int col4 = t & 15, rowg = t >> 4;
    float4 s4 = make_float4(0.f, 0.f, 0.f, 0.f);
    float4 q4 = make_float4(0.f, 0.f, 0.f, 0.f);
    float4* outv = (float4*)out;
    #pragma unroll
    for (int r = rowg; r < RPB; r += 16) {
        float4 v = *(const float4*)&accs[r * ASTRIDE + col4 * 4];
        outv[(size_t)(b * RPB + r) * 16 + col4] = v;
        s4.x += v.x; s4.y += v.y; s4.z += v.z; s4.w += v.w;
        q4.x = fmaf(v.x, v.x, q4.x); q4.y = fmaf(v.y, v.y, q4.y);
        q4.z = fmaf(v.z, v.z, q4.z); q4.w = fmaf(v.w, v.w, q4.w);
    }
    __syncthreads();
    float4* sc = (float4*)accs;
    sc[t] = s4; sc[256 + t] = q4;
    __syncthreads();
    if (t < 16) {
        float4 ts = make_float4(0.f, 0.f, 0.f, 0.f);
        float4 tq = make_float4(0.f, 0.f, 0.f, 0.f);
        for (int j = 0; j < 16; ++j) {
            float4 a  = sc[j * 16 + t];
            float4 bq = sc[256 + j * 16 + t];
            ts.x += a.x; ts.y += a.y; ts.z += a.z; ts.w += a.w;
            tq.x += bq.x; tq.y += bq.y; tq.z += bq.z; tq.w += bq.w;
        }
        const int c0i = t * 4;
        unsafeAtomicAdd(&stats[c0i + 0], ts.x);
        unsafeAtomicAdd(&stats[c0i + 1], ts.y);
        unsafeAtomicAdd(&stats[c0i + 2], ts.z);
        unsafeAtomicAdd(&stats[c0i + 3], ts.w);
        unsafeAtomicAdd(&stats[C + c0i + 0], tq.x);
        unsafeAtomicAdd(&stats[C + c0i + 1], tq.y);
        unsafeAtomicAdd(&stats[C + c0i + 2], tq.z);
        unsafeAtomicAdd(&stats[C + c0i + 3], tq.w);
    }
}

// ---------------------------------------------------------------------------
// In-place BN (affine) + LeakyReLU, float4-vectorized.
// ---------------------------------------------------------------------------
__global__ __launch_bounds__(256) void bn_kernel(
    float* __restrict__ out, const float* __restrict__ stats,
    const float* __restrict__ gamma, const float* __restrict__ beta)
{
    __shared__ __align__(16) float s_scale[C];
    __shared__ __align__(16) float s_shift[C];
    if (threadIdx.x < C) {
        const float inv_n = 1.0f / (float)N_OUT;
        float mean = stats[threadIdx.x] * inv_n;
        float var  = stats[C + threadIdx.x] * inv_n - mean * mean;
        float sc   = gamma[threadIdx.x] * rsqrtf(var + EPS);
        s_scale[threadIdx.x] = sc;
        s_shift[threadIdx.x] = beta[threadIdx.x] - mean * sc;
    }
    __syncthreads();

    const int col4 = threadIdx.x & 15;
    const int rowg = threadIdx.x >> 4;
    const float4 sc4 = *(const float4*)&s_scale[col4 * 4];
    const float4 sh4 = *(const float4*)&s_shift[col4 * 4];

    for (int row = blockIdx.x * 16 + rowg; row < N_OUT; row += gridDim.x * 16) {
        float4* p = (float4*)(out + (size_t)row * C + col4 * 4);
        float4 v = *p;
        v.x = fmaf(v.x, sc4.x, sh4.x);
        v.y = fmaf(v.y, sc4.y, sh4.y);
        v.z = fmaf(v.z, sc4.z, sh4.z);
        v.w = fmaf(v.w, sc4.w, sh4.w);
        v.x = v.x >= 0.f ? v.x : NEG_SLOPE * v.x;
        v.y = v.y >= 0.f ? v.y : NEG_SLOPE * v.y;
        v.z = v.z >= 0.f ? v.z : NEG_SLOPE * v.z;
        v.w = v.w >= 0.f ? v.w : NEG_SLOPE * v.w;
        *p = v;
    }
}

extern "C" void kernel_launch(void* const* d_in, const int* in_sizes, int n_in,
                              void* d_out, int out_size, void* d_ws, size_t ws_size,
                              hipStream_t stream) {
    const float* feats  = (const float*)d_in[0];
    const float* W      = (const float*)d_in[1];
    const float* gamma  = (const float*)d_in[2];
    const float* beta   = (const float*)d_in[3];
    const int*  in_map  = (const int*)d_in[4];
    const int*  out_map = (const int*)d_in[5];

    float* out = (float*)d_out;

    // workspace layout (~15.3 MB)
    u32* counts  = (u32*)d_ws;               // NKEY
    u32* partial = counts  + NKEY;           // NKEY
    u32* bsums   = partial + NKEY;           // 256
    u32* offsets = bsums   + 256;            // NKEY+1 (+pad)
    u32* cursor  = offsets + NKEY + 16;      // NKEY
    u32* sorted  = cursor  + NKEY;           // NTOT
    float* stats = (float*)(sorted + NTOT);  // 128  (16B-aligned)
    _Float16* Bh = (_Float16*)(stats + 128); // 13824*8 fp16 = 216 KB (16B-aligned)

    hipMemsetAsync(counts, 0, NKEY * sizeof(u32), stream);
    hipMemsetAsync(stats, 0, 2 * C * sizeof(float), stream);

    prep_kernel   <<<54,         256, 0, stream>>>(W, Bh);
    hist_kernel   <<<NTOT / 256, 256, 0, stream>>>(out_map, counts);
    scan1_kernel  <<<SCANB,      256, 0, stream>>>(counts, partial, bsums);
    scan2_kernel  <<<1,          256, 0, stream>>>(bsums);
    scan3_kernel  <<<SCANB,      256, 0, stream>>>(partial, bsums, offsets, cursor);
    scatter_kernel<<<NTOT / 256, 256, 0, stream>>>(in_map, out_map, cursor, sorted);
    gather_kernel <<<NBLK,       256, 0, stream>>>(feats, (const half8*)Bh, offsets, sorted, out, stats);
    bn_kernel     <<<512,        256, 0, stream>>>(out, stats, gamma, beta);
}